// Round 8
// baseline (133.398 us; speedup 1.0000x reference)
//
#include <hip/hip_runtime.h>
#include <hip/hip_bf16.h>

// X: [16, 2048, 128] f32, Y: [16, 2048, 128] f32 -> out: [16, 2048, 2048] f32
// out[b,n,m] = 1/(1+sqrt(max(||x||^2+||y||^2-2 x.y, 1e-7)))
#define Bb   16
#define Nn   2048
#define Mm   2048
#define Dd   128
#define TILE 128
#define NBLK 512    // 2 blocks/CU exactly (write-clean regime, R0-R7 evidence)
#define TPB  8      // Y tiles per block

typedef __attribute__((ext_vector_type(4))) float          f32x4;
typedef __attribute__((ext_vector_type(8))) unsigned short u16x8;
typedef __attribute__((ext_vector_type(8))) __bf16         bf16x8;

__device__ __forceinline__ unsigned short f32_to_bf16_rne(float f) {
  unsigned int u = __builtin_bit_cast(unsigned int, f);
  u += 0x7fffu + ((u >> 16) & 1u);
  return (unsigned short)(u >> 16);
}

// Persistent-ish: one block = one (batch, bn, bm-half); X panel staged ONCE,
// then 8 Y tiles pipelined: Y(t+1) global->reg prefetch issued before tile t's
// MFMA+epilogue (latency hidden under compute), reg->LDS after the barrier.
// LDS = 65.5 KB -> 2 blocks/CU = 16 waves/CU; 128x128 tiles keep L2 store-merge
// clean. Blocks desynchronize -> smooth HBM streams instead of grid convoys.
__global__ __launch_bounds__(512, 4)
void dist_sim_kernel(const float* __restrict__ X, const float* __restrict__ Y,
                     float* __restrict__ out) {
  __shared__ alignas(16) unsigned short Xs[TILE * Dd];  // 32 KB bf16, swizzled
  __shared__ alignas(16) unsigned short Ys[TILE * Dd];  // 32 KB
  __shared__ alignas(16) float xsq[TILE];
  __shared__ alignas(16) float ysq[TILE];

  const int tid = threadIdx.x;

  // XCD-chunked (512 % 8 == 0): XCD x owns swz [x*64, x*64+64) = 2 batches.
  const int gid = blockIdx.x;
  const int swz = (gid & 7) * (NBLK / 8) + (gid >> 3);
  const int b   = swz >> 5;          // 0..15
  const int bn  = (swz >> 1) & 15;   // 0..15
  const int bmh = swz & 1;           // 0..1 -> bm = bmh*8 + t

  const float* Xb = X + ((size_t)b * Nn + (size_t)bn * TILE) * Dd;
  const float* Yb = Y + (size_t)b * Mm * Dd + (size_t)bmh * 8 * TILE * Dd;

  // Staging map: 4 threads per 128-float row; thread covers 32 floats.
  const int row = tid >> 2;          // 0..127
  const int c0  = (tid & 3) * 32;    // 0,32,64,96

  // ---- prologue: stage X panel once (bf16 LDS + f32 norms) -----------------
  {
    const float* px = Xb + row * Dd + c0;
    f32x4 v[8];
    #pragma unroll
    for (int q = 0; q < 8; ++q) v[q] = *(const f32x4*)(px + 4 * q);
    float sx = 0.f;
    #pragma unroll
    for (int q = 0; q < 4; ++q) {
      u16x8 w;
      #pragma unroll
      for (int e = 0; e < 4; ++e) {
        const float x0 = v[2 * q][e], x1 = v[2 * q + 1][e];
        sx += x0 * x0 + x1 * x1;
        w[e] = f32_to_bf16_rne(x0); w[e + 4] = f32_to_bf16_rne(x1);
      }
      const int idx = (row * Dd + c0 + q * 8) ^ ((row & 7) << 3);
      *(u16x8*)&Xs[idx] = w;
    }
    sx += __shfl_xor(sx, 1);
    sx += __shfl_xor(sx, 2);
    if ((tid & 3) == 0) xsq[row] = sx;
  }

  const int lane = tid & 63;
  const int wid  = tid >> 6;           // 0..7
  const int wr   = (wid >> 2) * 64;    // 0 or 64
  const int wc   = (wid & 3) * 32;     // 0,32,64,96
  const int fr   = lane & 15;
  const int kg   = lane >> 4;          // 0..3

  // ---- prologue: Y tile 0 -> regs -> LDS ----------------------------------
  f32x4 yreg[8];
  {
    const float* py = Yb + row * Dd + c0;   // tile 0
    #pragma unroll
    for (int q = 0; q < 8; ++q) yreg[q] = *(const f32x4*)(py + 4 * q);
  }
  {
    float sy = 0.f;
    #pragma unroll
    for (int q = 0; q < 4; ++q) {
      u16x8 w;
      #pragma unroll
      for (int e = 0; e < 4; ++e) {
        const float y0 = yreg[2 * q][e], y1 = yreg[2 * q + 1][e];
        sy += y0 * y0 + y1 * y1;
        w[e] = f32_to_bf16_rne(y0); w[e + 4] = f32_to_bf16_rne(y1);
      }
      const int idx = (row * Dd + c0 + q * 8) ^ ((row & 7) << 3);
      *(u16x8*)&Ys[idx] = w;
    }
    sy += __shfl_xor(sy, 1);
    sy += __shfl_xor(sy, 2);
    if ((tid & 3) == 0) ysq[row] = sy;
  }
  __syncthreads();

  float xv[4];
  #pragma unroll
  for (int i = 0; i < 4; ++i) xv[i] = xsq[wr + i * 16 + fr];

  float* outb0 = out + (size_t)b * Nn * Mm + (size_t)(bn * TILE) * Mm
               + (size_t)bmh * 8 * TILE;

  // ---- main loop over 8 Y tiles -------------------------------------------
  #pragma unroll
  for (int t = 0; t < TPB; ++t) {
    // Prefetch Y tile t+1 into regs (latency hides under MFMA + epilogue).
    if (t < TPB - 1) {
      const float* py = Yb + (size_t)(t + 1) * TILE * Dd + row * Dd + c0;
      #pragma unroll
      for (int q = 0; q < 8; ++q) yreg[q] = *(const f32x4*)(py + 4 * q);
    }

    // MFMA: swapped operands, D[m-frag][n-frag].
    // acc[i][j] (lane fr,kg; reg r): n = wr+i*16+fr, m = wc+j*16+kg*4+r
    f32x4 acc[4][2];
    #pragma unroll
    for (int i = 0; i < 4; ++i)
      #pragma unroll
      for (int j = 0; j < 2; ++j)
        acc[i][j] = (f32x4){0.f, 0.f, 0.f, 0.f};

    #pragma unroll
    for (int kk = 0; kk < 4; ++kk) {
      const int k0 = kk * 32 + kg * 8;
      bf16x8 a[4], bb[2];
      #pragma unroll
      for (int i = 0; i < 4; ++i) {
        const int r_ = wr + i * 16 + fr;
        const int idx = (r_ * Dd + k0) ^ ((r_ & 7) << 3);
        a[i] = __builtin_bit_cast(bf16x8, *(const u16x8*)&Xs[idx]);
      }
      #pragma unroll
      for (int j = 0; j < 2; ++j) {
        const int r_ = wc + j * 16 + fr;
        const int idx = (r_ * Dd + k0) ^ ((r_ & 7) << 3);
        bb[j] = __builtin_bit_cast(bf16x8, *(const u16x8*)&Ys[idx]);
      }
      #pragma unroll
      for (int i = 0; i < 4; ++i)
        #pragma unroll
        for (int j = 0; j < 2; ++j)
          acc[i][j] = __builtin_amdgcn_mfma_f32_16x16x32_bf16(bb[j], a[i], acc[i][j], 0, 0, 0);
    }

    // Epilogue for tile t; j=0,1 stores complete each 128B line per wave.
    f32x4 yv[2];
    #pragma unroll
    for (int j = 0; j < 2; ++j) yv[j] = *(const f32x4*)&ysq[wc + j * 16 + kg * 4];

    float* outb = outb0 + (size_t)t * TILE;
    #pragma unroll
    for (int i = 0; i < 4; ++i) {
      float* orow = outb + (size_t)(wr + i * 16 + fr) * Mm;
      #pragma unroll
      for (int j = 0; j < 2; ++j) {
        f32x4 ov;
        #pragma unroll
        for (int r = 0; r < 4; ++r) {
          float d2 = fmaf(-2.0f, acc[i][j][r], xv[i] + yv[j][r]);
          d2 = fmaxf(d2, 1e-7f);
          ov[r] = __builtin_amdgcn_rcpf(1.0f + __builtin_amdgcn_sqrtf(d2));
        }
        *(f32x4*)&orow[wc + j * 16 + kg * 4] = ov;
      }
    }

    // Publish Y tile t+1: barrier (MFMA LDS reads done), write, barrier.
    if (t < TPB - 1) {
      __syncthreads();
      float sy = 0.f;
      #pragma unroll
      for (int q = 0; q < 4; ++q) {
        u16x8 w;
        #pragma unroll
        for (int e = 0; e < 4; ++e) {
          const float y0 = yreg[2 * q][e], y1 = yreg[2 * q + 1][e];
          sy += y0 * y0 + y1 * y1;
          w[e] = f32_to_bf16_rne(y0); w[e + 4] = f32_to_bf16_rne(y1);
        }
        const int idx = (row * Dd + c0 + q * 8) ^ ((row & 7) << 3);
        *(u16x8*)&Ys[idx] = w;
      }
      sy += __shfl_xor(sy, 1);
      sy += __shfl_xor(sy, 2);
      if ((tid & 3) == 0) ysq[row] = sy;
      __syncthreads();
    }
  }
}

extern "C" void kernel_launch(void* const* d_in, const int* in_sizes, int n_in,
                              void* d_out, int out_size, void* d_ws, size_t ws_size,
                              hipStream_t stream) {
  const float* X = (const float*)d_in[0];
  const float* Y = (const float*)d_in[1];
  float* out = (float*)d_out;
  dist_sim_kernel<<<dim3(NBLK), dim3(512, 1, 1), 0, stream>>>(X, Y, out);
}